// Round 1
// baseline (2662.949 us; speedup 1.0000x reference)
//
#include <hip/hip_runtime.h>
#include <hip/hip_bf16.h>

#define Bq 4
#define Sq 2048
#define Dq 512
#define Hq 8
#define HDq 64
#define ROWS 8   // query rows per attention block (one per wave)

// ---------------- projection: C = X @ W^T + bias, written in head layout ----------------
// X: [8192, 512], W: [512, 512] (row n is output-neuron n), out: [B,H,S,HD]
__global__ __launch_bounds__(256)
void proj_kernel(const float* __restrict__ X, const float* __restrict__ W,
                 const float* __restrict__ bias, float* __restrict__ out) {
    __shared__ float Xs[64][17];
    __shared__ float Ws[64][17];
    const int tid = threadIdx.x;
    const int m0 = blockIdx.y * 64;
    const int n0 = blockIdx.x * 64;
    const int tr = tid >> 4;        // 0..15
    const int tc = tid & 15;        // 0..15
    const int lr = tid >> 2;        // staging row 0..63
    const int lk = (tid & 3) << 2;  // staging k offset 0,4,8,12

    float acc[4][4];
    #pragma unroll
    for (int i = 0; i < 4; ++i)
        #pragma unroll
        for (int j = 0; j < 4; ++j) acc[i][j] = 0.f;

    for (int k0 = 0; k0 < Dq; k0 += 16) {
        float4 xv = *(const float4*)(X + (size_t)(m0 + lr) * Dq + k0 + lk);
        float4 wv = *(const float4*)(W + (size_t)(n0 + lr) * Dq + k0 + lk);
        __syncthreads();   // previous iteration's readers done before overwrite
        Xs[lr][lk + 0] = xv.x; Xs[lr][lk + 1] = xv.y; Xs[lr][lk + 2] = xv.z; Xs[lr][lk + 3] = xv.w;
        Ws[lr][lk + 0] = wv.x; Ws[lr][lk + 1] = wv.y; Ws[lr][lk + 2] = wv.z; Ws[lr][lk + 3] = wv.w;
        __syncthreads();
        #pragma unroll
        for (int k = 0; k < 16; ++k) {
            float a0 = Xs[tr * 4 + 0][k], a1 = Xs[tr * 4 + 1][k];
            float a2 = Xs[tr * 4 + 2][k], a3 = Xs[tr * 4 + 3][k];
            float b0 = Ws[tc * 4 + 0][k], b1 = Ws[tc * 4 + 1][k];
            float b2 = Ws[tc * 4 + 2][k], b3 = Ws[tc * 4 + 3][k];
            acc[0][0] += a0 * b0; acc[0][1] += a0 * b1; acc[0][2] += a0 * b2; acc[0][3] += a0 * b3;
            acc[1][0] += a1 * b0; acc[1][1] += a1 * b1; acc[1][2] += a1 * b2; acc[1][3] += a1 * b3;
            acc[2][0] += a2 * b0; acc[2][1] += a2 * b1; acc[2][2] += a2 * b2; acc[2][3] += a2 * b3;
            acc[3][0] += a3 * b0; acc[3][1] += a3 * b1; acc[3][2] += a3 * b2; acc[3][3] += a3 * b3;
        }
    }

    #pragma unroll
    for (int i = 0; i < 4; ++i) {
        #pragma unroll
        for (int j = 0; j < 4; ++j) {
            int m = m0 + tr * 4 + i;
            int n = n0 + tc * 4 + j;
            int b = m >> 11, s = m & 2047;
            int h = n >> 6,  hd = n & 63;
            out[((((size_t)b * Hq + h) * Sq + s) << 6) + hd] = acc[i][j] + bias[n];
        }
    }
}

// ---------------- attention: per-wave query row, online dual softmax ----------------
// Qh/Kh/Vh: [B*H, S, 64]. part: [numBlocks, 64] partial head_logits contributions.
__global__ __launch_bounds__(512, 2)
void attn_kernel(const float* __restrict__ Qh, const float* __restrict__ Kh,
                 const float* __restrict__ Vh, float* __restrict__ part) {
    __shared__ float Ks[64][68];
    __shared__ float Vs[64][68];
    __shared__ float qs[ROWS][68];

    const int tid  = threadIdx.x;
    const int lane = tid & 63;
    const int w    = tid >> 6;                 // wave id 0..7
    const int bh   = blockIdx.x >> 8;          // 256 blocks per (b,h)
    const int s0   = (blockIdx.x & 255) * ROWS;
    const size_t base = (size_t)bh * Sq * HDq;

    // stage this block's 8 query rows (each wave writes its own row)
    qs[w][lane] = Qh[base + (size_t)(s0 + w) * HDq + lane];

    float acc_k[64], acc_v[64];
    #pragma unroll
    for (int d = 0; d < 64; ++d) { acc_k[d] = 0.f; acc_v[d] = 0.f; }
    float m_k = -INFINITY, m_v = -INFINITY;
    float l_k = 0.f, l_v = 0.f;
    const float scale = 0.125f;  // 1/sqrt(64)

    for (int c = 0; c < Sq / 64; ++c) {
        __syncthreads();
        // stage 64 K rows + 64 V rows (each 64 floats): 1024 float4 per array, 512 threads
        #pragma unroll
        for (int f = 0; f < 2; ++f) {
            int idx = f * 512 + tid;
            int r  = idx >> 4;
            int c4 = (idx & 15) << 2;
            float4 kv = *(const float4*)(Kh + base + (size_t)(c * 64 + r) * HDq + c4);
            float4 vv = *(const float4*)(Vh + base + (size_t)(c * 64 + r) * HDq + c4);
            *(float4*)&Ks[r][c4] = kv;
            *(float4*)&Vs[r][c4] = vv;
        }
        __syncthreads();

        // scores: lane j handles k-row j of this chunk
        float sk = 0.f, sv = 0.f;
        #pragma unroll
        for (int d4 = 0; d4 < 64; d4 += 4) {
            float4 q4 = *(const float4*)&qs[w][d4];
            float4 k4 = *(const float4*)&Ks[lane][d4];
            float4 v4 = *(const float4*)&Vs[lane][d4];
            sk += q4.x * k4.x + q4.y * k4.y + q4.z * k4.z + q4.w * k4.w;
            sv += q4.x * v4.x + q4.y * v4.y + q4.z * v4.z + q4.w * v4.w;
        }
        sk *= scale; sv *= scale;

        // wave max of both score sets
        float cmk = sk, cmv = sv;
        #pragma unroll
        for (int off = 32; off; off >>= 1) {
            cmk = fmaxf(cmk, __shfl_xor(cmk, off));
            cmv = fmaxf(cmv, __shfl_xor(cmv, off));
        }
        // defer-max: rescale only when the chunk max meaningfully exceeds running max
        if (cmk > m_k + 8.f) {
            float a = __expf(m_k - cmk);      // first chunk: exp(-inf)=0, accs already 0
            l_k *= a;
            #pragma unroll
            for (int d = 0; d < 64; ++d) acc_k[d] *= a;
            m_k = cmk;
        }
        if (cmv > m_v + 8.f) {
            float a = __expf(m_v - cmv);
            l_v *= a;
            #pragma unroll
            for (int d = 0; d < 64; ++d) acc_v[d] *= a;
            m_v = cmv;
        }
        float pk = __expf(sk - m_k);
        float pv = __expf(sv - m_v);
        l_k += pk; l_v += pv;

        // accumulate: acc_*[d] += p_* * (K[j][d] + V[j][d])   (j = lane's k-row)
        #pragma unroll
        for (int d4 = 0; d4 < 64; d4 += 4) {
            float4 k4 = *(const float4*)&Ks[lane][d4];
            float4 v4 = *(const float4*)&Vs[lane][d4];
            float f0 = k4.x + v4.x, f1 = k4.y + v4.y, f2 = k4.z + v4.z, f3 = k4.w + v4.w;
            acc_k[d4 + 0] += pk * f0; acc_v[d4 + 0] += pv * f0;
            acc_k[d4 + 1] += pk * f1; acc_v[d4 + 1] += pv * f1;
            acc_k[d4 + 2] += pk * f2; acc_v[d4 + 2] += pv * f2;
            acc_k[d4 + 3] += pk * f3; acc_v[d4 + 3] += pv * f3;
        }
    }

    // wave-sum the per-lane softmax denominators
    #pragma unroll
    for (int off = 32; off; off >>= 1) {
        l_k += __shfl_xor(l_k, off);
        l_v += __shfl_xor(l_v, off);
    }
    float ilk = 1.0f / l_k;
    float ilv = 1.0f / l_v;

    // per-lane contribution vector: contrib[d] = attended_partial[d] * q[row][d]
    #pragma unroll
    for (int d4 = 0; d4 < 64; d4 += 4) {
        float4 q4 = *(const float4*)&qs[w][d4];
        acc_k[d4 + 0] = (acc_k[d4 + 0] * ilk + acc_v[d4 + 0] * ilv) * q4.x;
        acc_k[d4 + 1] = (acc_k[d4 + 1] * ilk + acc_v[d4 + 1] * ilv) * q4.y;
        acc_k[d4 + 2] = (acc_k[d4 + 2] * ilk + acc_v[d4 + 2] * ilv) * q4.z;
        acc_k[d4 + 3] = (acc_k[d4 + 3] * ilk + acc_v[d4 + 3] * ilv) * q4.w;
    }

    // fold-reduce across lanes: lane d ends with sum over all 64 k-lanes of contrib[d]
    #pragma unroll
    for (int s = 32; s >= 1; s >>= 1) {
        #pragma unroll
        for (int d2 = 0; d2 < s; ++d2) {
            bool up = (lane & s) != 0;
            float send = up ? acc_k[d2] : acc_k[d2 + s];
            float keep = up ? acc_k[d2 + s] : acc_k[d2];
            acc_k[d2] = keep + __shfl_xor(send, s);
        }
    }

    // combine 8 waves via LDS (reuse qs), then one partial row per block
    qs[w][lane] = acc_k[0];
    __syncthreads();
    if (tid < 64) {
        float t = 0.f;
        #pragma unroll
        for (int r = 0; r < ROWS; ++r) t += qs[r][tid];
        part[(size_t)blockIdx.x * 64 + tid] = t;
    }
}

// ---------------- deterministic final reduction over blocks ----------------
__global__ void reduce_kernel(const float* __restrict__ part, float* __restrict__ out) {
    int bh = blockIdx.x;     // 0..31
    int d  = threadIdx.x;    // 0..63
    float t = 0.f;
    for (int i = 0; i < Sq / ROWS; ++i)
        t += part[(size_t)(bh * (Sq / ROWS) + i) * 64 + d];
    out[bh * 64 + d] = t;
}

extern "C" void kernel_launch(void* const* d_in, const int* in_sizes, int n_in,
                              void* d_out, int out_size, void* d_ws, size_t ws_size,
                              hipStream_t stream) {
    const float* value = (const float*)d_in[0];
    const float* key   = (const float*)d_in[1];
    const float* query = (const float*)d_in[2];
    const float* Wv    = (const float*)d_in[3];
    const float* bv    = (const float*)d_in[4];
    const float* Wk    = (const float*)d_in[5];
    const float* bk    = (const float*)d_in[6];
    const float* Wq    = (const float*)d_in[7];
    const float* bq    = (const float*)d_in[8];
    float* out = (float*)d_out;

    float* ws   = (float*)d_ws;
    float* Qh   = ws;                  // 4,194,304 floats (16 MB)
    float* Kh   = ws + 4194304;
    float* Vh   = ws + 8388608;
    float* part = ws + 12582912;       // 8192 * 64 floats (2 MB)

    dim3 pg(Dq / 64, (Bq * Sq) / 64);  // (8, 128)
    proj_kernel<<<pg, 256, 0, stream>>>(query, Wq, bq, Qh);
    proj_kernel<<<pg, 256, 0, stream>>>(key,   Wk, bk, Kh);
    proj_kernel<<<pg, 256, 0, stream>>>(value, Wv, bv, Vh);

    attn_kernel<<<(Bq * Hq * Sq) / ROWS, 512, 0, stream>>>(Qh, Kh, Vh, part);
    reduce_kernel<<<Bq * Hq, 64, 0, stream>>>(part, out);
}

// Round 2
// 487.070 us; speedup vs baseline: 5.4673x; 5.4673x over previous
//
#include <hip/hip_runtime.h>
#include <hip/hip_bf16.h>

#define Bq 4
#define Sq 2048
#define Dq 512
#define Hq 8
#define HDq 64

typedef __attribute__((ext_vector_type(8))) short short8;
typedef __attribute__((ext_vector_type(4))) float f32x4;

#if __has_builtin(__builtin_amdgcn_exp2f)
#define EXP2(x) __builtin_amdgcn_exp2f(x)
#else
#define EXP2(x) exp2f(x)
#endif

// scale * log2(e): softmax computed in base-2 domain
#define SCALE2 (0.125f * 1.44269504088896340736f)

// ---------------- projection: C = X @ W^T + bias, bf16 out in head layout ----------------
__global__ __launch_bounds__(256)
void proj_kernel(const float* __restrict__ X, const float* __restrict__ W,
                 const float* __restrict__ bias, __hip_bfloat16* __restrict__ out) {
    __shared__ float Xs[64][17];
    __shared__ float Ws[64][17];
    const int tid = threadIdx.x;
    const int m0 = blockIdx.y * 64;
    const int n0 = blockIdx.x * 64;
    const int tr = tid >> 4;
    const int tc = tid & 15;
    const int lr = tid >> 2;
    const int lk = (tid & 3) << 2;

    float acc[4][4];
    #pragma unroll
    for (int i = 0; i < 4; ++i)
        #pragma unroll
        for (int j = 0; j < 4; ++j) acc[i][j] = 0.f;

    for (int k0 = 0; k0 < Dq; k0 += 16) {
        float4 xv = *(const float4*)(X + (size_t)(m0 + lr) * Dq + k0 + lk);
        float4 wv = *(const float4*)(W + (size_t)(n0 + lr) * Dq + k0 + lk);
        __syncthreads();
        Xs[lr][lk + 0] = xv.x; Xs[lr][lk + 1] = xv.y; Xs[lr][lk + 2] = xv.z; Xs[lr][lk + 3] = xv.w;
        Ws[lr][lk + 0] = wv.x; Ws[lr][lk + 1] = wv.y; Ws[lr][lk + 2] = wv.z; Ws[lr][lk + 3] = wv.w;
        __syncthreads();
        #pragma unroll
        for (int k = 0; k < 16; ++k) {
            float a0 = Xs[tr * 4 + 0][k], a1 = Xs[tr * 4 + 1][k];
            float a2 = Xs[tr * 4 + 2][k], a3 = Xs[tr * 4 + 3][k];
            float b0 = Ws[tc * 4 + 0][k], b1 = Ws[tc * 4 + 1][k];
            float b2 = Ws[tc * 4 + 2][k], b3 = Ws[tc * 4 + 3][k];
            acc[0][0] += a0 * b0; acc[0][1] += a0 * b1; acc[0][2] += a0 * b2; acc[0][3] += a0 * b3;
            acc[1][0] += a1 * b0; acc[1][1] += a1 * b1; acc[1][2] += a1 * b2; acc[1][3] += a1 * b3;
            acc[2][0] += a2 * b0; acc[2][1] += a2 * b1; acc[2][2] += a2 * b2; acc[2][3] += a2 * b3;
            acc[3][0] += a3 * b0; acc[3][1] += a3 * b1; acc[3][2] += a3 * b2; acc[3][3] += a3 * b3;
        }
    }

    #pragma unroll
    for (int i = 0; i < 4; ++i) {
        #pragma unroll
        for (int j = 0; j < 4; ++j) {
            int m = m0 + tr * 4 + i;
            int n = n0 + tc * 4 + j;
            int b = m >> 11, s = m & 2047;
            int h = n >> 6,  hd = n & 63;
            out[((((size_t)b * Hq + h) * Sq + s) << 6) + hd] = __float2bfloat16(acc[i][j] + bias[n]);
        }
    }
}

// ---------------- F^T = (K+V)^T per head: Ft[bh][d][s] ----------------
__global__ __launch_bounds__(256)
void fuse_t_kernel(const __hip_bfloat16* __restrict__ Kh, const __hip_bfloat16* __restrict__ Vh,
                   __hip_bfloat16* __restrict__ Ft) {
    __shared__ float T[64][65];
    const int bh = blockIdx.x >> 5;
    const int st = blockIdx.x & 31;
    const int tid = threadIdx.x;

    #pragma unroll
    for (int p = 0; p < 2; ++p) {
        int idx = p * 256 + tid;
        int r = idx >> 3;           // s row within tile
        int c = (idx & 7) * 8;      // d offset
        size_t g = ((size_t)bh * Sq + st * 64 + r) * 64 + c;
        float4 k4 = *(const float4*)((const char*)Kh + g * 2);
        float4 v4 = *(const float4*)((const char*)Vh + g * 2);
        const __hip_bfloat16* kp = (const __hip_bfloat16*)&k4;
        const __hip_bfloat16* vp = (const __hip_bfloat16*)&v4;
        #pragma unroll
        for (int j = 0; j < 8; ++j)
            T[r][c + j] = __bfloat162float(kp[j]) + __bfloat162float(vp[j]);
    }
    __syncthreads();
    #pragma unroll
    for (int p = 0; p < 2; ++p) {
        int idx = p * 256 + tid;
        int d  = idx >> 3;
        int s8 = (idx & 7) * 8;
        alignas(16) __hip_bfloat16 tmp[8];
        #pragma unroll
        for (int j = 0; j < 8; ++j) tmp[j] = __float2bfloat16(T[s8 + j][d]);
        *(float4*)((char*)Ft + (((size_t)bh * 64 + d) * Sq + st * 64 + s8) * 2) = *(const float4*)tmp;
    }
}

// ---------------- MFMA attention: 1 block = 1 (b,h) x 64 q-rows, 4 waves ----------------
__global__ __launch_bounds__(256)
void attn_kernel(const __hip_bfloat16* __restrict__ Qh, const __hip_bfloat16* __restrict__ Kh,
                 const __hip_bfloat16* __restrict__ Vh, const __hip_bfloat16* __restrict__ Ft,
                 float* __restrict__ part) {
    __shared__ alignas(16) short Qs[64 * 64];
    __shared__ alignas(16) short Ks[64 * 64];
    __shared__ alignas(16) short Vs[64 * 64];
    __shared__ alignas(16) short Fs[64 * 64];
    __shared__ alignas(16) short Pk[4 * 16 * 64];
    __shared__ alignas(16) short Pv[4 * 16 * 64];
    __shared__ float part_s[4][64];

    const int tid  = threadIdx.x;
    const int lane = tid & 63;
    const int w    = tid >> 6;
    const int bh   = blockIdx.x >> 5;
    const int s0   = (blockIdx.x & 31) * 64;

    const char* Qbh = (const char*)(Qh + (size_t)bh * Sq * 64);
    const char* Kbh = (const char*)(Kh + (size_t)bh * Sq * 64);
    const char* Vbh = (const char*)(Vh + (size_t)bh * Sq * 64);
    const char* Fbh = (const char*)(Ft + (size_t)bh * 64 * Sq);

    // ---- stage Q tile (64 rows x 64 dims, swizzled) ----
    #pragma unroll
    for (int p = 0; p < 2; ++p) {
        int idx = p * 256 + tid;
        int r = idx >> 3;
        int c = idx & 7;
        int swz = (r & 7) << 4;
        float4 q4 = *(const float4*)(Qbh + ((size_t)(s0 + r) * 64 + c * 8) * 2);
        *(float4*)((char*)Qs + r * 128 + ((c * 16) ^ swz)) = q4;
    }
    __syncthreads();

    const int arow = lane & 15;          // A-frag row within 16
    const int ag   = lane >> 4;          // lane group 0..3
    const int aswz = (arow & 7) << 4;

    // hoist Q A-fragments (static for whole KV sweep)
    const int qrow = w * 16 + arow;
    short8 qa0 = *(const short8*)((const char*)Qs + qrow * 128 + ((16 * ag) ^ aswz));
    short8 qa1 = *(const short8*)((const char*)Qs + qrow * 128 + ((64 + 16 * ag) ^ aswz));

    char* PkW = (char*)Pk + w * 2048;
    char* PvW = (char*)Pv + w * 2048;

    f32x4 acc_k[4], acc_v[4];
    #pragma unroll
    for (int t = 0; t < 4; ++t) {
        acc_k[t] = (f32x4){0.f, 0.f, 0.f, 0.f};
        acc_v[t] = (f32x4){0.f, 0.f, 0.f, 0.f};
    }
    float m_k[4], m_v[4], lp_k[4], lp_v[4];
    #pragma unroll
    for (int r = 0; r < 4; ++r) {
        m_k[r] = -INFINITY; m_v[r] = -INFINITY;
        lp_k[r] = 0.f; lp_v[r] = 0.f;
    }

    for (int ck = 0; ck < Sq / 64; ++ck) {
        const int kv0 = ck * 64;
        __syncthreads();   // prior chunk's LDS readers done
        // ---- stage K, V, F^T chunks (swizzled) ----
        #pragma unroll
        for (int p = 0; p < 2; ++p) {
            int idx = p * 256 + tid;
            int r = idx >> 3;
            int c = idx & 7;
            int swz = (r & 7) << 4;
            float4 k4 = *(const float4*)(Kbh + ((size_t)(kv0 + r) * 64 + c * 8) * 2);
            float4 v4 = *(const float4*)(Vbh + ((size_t)(kv0 + r) * 64 + c * 8) * 2);
            float4 f4 = *(const float4*)(Fbh + ((size_t)r * Sq + kv0 + c * 8) * 2);
            *(float4*)((char*)Ks + r * 128 + ((c * 16) ^ swz)) = k4;
            *(float4*)((char*)Vs + r * 128 + ((c * 16) ^ swz)) = v4;
            *(float4*)((char*)Fs + r * 128 + ((c * 16) ^ swz)) = f4;
        }
        __syncthreads();

        // ---- scores: S_k = Q K^T, S_v = Q V^T  (wave: 16 q-rows x 64 kv) ----
        f32x4 sk[4], sv[4];
        #pragma unroll
        for (int t = 0; t < 4; ++t) {
            sk[t] = (f32x4){0.f, 0.f, 0.f, 0.f};
            sv[t] = (f32x4){0.f, 0.f, 0.f, 0.f};
        }
        #pragma unroll
        for (int t = 0; t < 4; ++t) {
            int brow = t * 16 + arow;
            int bswz = (brow & 7) << 4;
            short8 kb0 = *(const short8*)((const char*)Ks + brow * 128 + ((16 * ag) ^ bswz));
            short8 kb1 = *(const short8*)((const char*)Ks + brow * 128 + ((64 + 16 * ag) ^ bswz));
            short8 vb0 = *(const short8*)((const char*)Vs + brow * 128 + ((16 * ag) ^ bswz));
            short8 vb1 = *(const short8*)((const char*)Vs + brow * 128 + ((64 + 16 * ag) ^ bswz));
            sk[t] = __builtin_amdgcn_mfma_f32_16x16x32_bf16(qa0, kb0, sk[t], 0, 0, 0);
            sk[t] = __builtin_amdgcn_mfma_f32_16x16x32_bf16(qa1, kb1, sk[t], 0, 0, 0);
            sv[t] = __builtin_amdgcn_mfma_f32_16x16x32_bf16(qa0, vb0, sv[t], 0, 0, 0);
            sv[t] = __builtin_amdgcn_mfma_f32_16x16x32_bf16(qa1, vb1, sv[t], 0, 0, 0);
        }

        // ---- online dual softmax (base-2), C-layout rows = 4*ag + r ----
        float cmk[4], cmv[4];
        #pragma unroll
        for (int r = 0; r < 4; ++r) {
            #pragma unroll
            for (int t = 0; t < 4; ++t) { sk[t][r] *= SCALE2; sv[t][r] *= SCALE2; }
            cmk[r] = fmaxf(fmaxf(sk[0][r], sk[1][r]), fmaxf(sk[2][r], sk[3][r]));
            cmv[r] = fmaxf(fmaxf(sv[0][r], sv[1][r]), fmaxf(sv[2][r], sv[3][r]));
        }
        #pragma unroll
        for (int off = 1; off < 16; off <<= 1) {
            #pragma unroll
            for (int r = 0; r < 4; ++r) {
                cmk[r] = fmaxf(cmk[r], __shfl_xor(cmk[r], off));
                cmv[r] = fmaxf(cmv[r], __shfl_xor(cmv[r], off));
            }
        }
        #pragma unroll
        for (int r = 0; r < 4; ++r) {
            if (cmk[r] > m_k[r] + 8.f) {
                float f = EXP2(m_k[r] - cmk[r]);
                m_k[r] = cmk[r]; lp_k[r] *= f;
                #pragma unroll
                for (int t = 0; t < 4; ++t) acc_k[t][r] *= f;
            }
            if (cmv[r] > m_v[r] + 8.f) {
                float f = EXP2(m_v[r] - cmv[r]);
                m_v[r] = cmv[r]; lp_v[r] *= f;
                #pragma unroll
                for (int t = 0; t < 4; ++t) acc_v[t][r] *= f;
            }
        }
        #pragma unroll
        for (int t = 0; t < 4; ++t) {
            #pragma unroll
            for (int r = 0; r < 4; ++r) {
                float pk = EXP2(sk[t][r] - m_k[r]);
                float pv = EXP2(sv[t][r] - m_v[r]);
                lp_k[r] += pk; lp_v[r] += pv;
                int row = 4 * ag + r;
                int col2 = (t * 16 + arow) * 2;
                int rswz = (row & 7) << 4;
                *(__hip_bfloat16*)(PkW + row * 128 + (col2 ^ rswz)) = __float2bfloat16(pk);
                *(__hip_bfloat16*)(PvW + row * 128 + (col2 ^ rswz)) = __float2bfloat16(pv);
            }
        }
        __syncthreads();   // P visible (and staged LDS stable until next top barrier)

        // ---- PV: acc += P @ F  (A from P, B from F^T) ----
        short8 pka0 = *(const short8*)(PkW + arow * 128 + ((16 * ag) ^ aswz));
        short8 pka1 = *(const short8*)(PkW + arow * 128 + ((64 + 16 * ag) ^ aswz));
        short8 pva0 = *(const short8*)(PvW + arow * 128 + ((16 * ag) ^ aswz));
        short8 pva1 = *(const short8*)(PvW + arow * 128 + ((64 + 16 * ag) ^ aswz));
        #pragma unroll
        for (int t = 0; t < 4; ++t) {
            int brow = t * 16 + arow;
            int bswz = (brow & 7) << 4;
            short8 fb0 = *(const short8*)((const char*)Fs + brow * 128 + ((16 * ag) ^ bswz));
            short8 fb1 = *(const short8*)((const char*)Fs + brow * 128 + ((64 + 16 * ag) ^ bswz));
            acc_k[t] = __builtin_amdgcn_mfma_f32_16x16x32_bf16(pka0, fb0, acc_k[t], 0, 0, 0);
            acc_k[t] = __builtin_amdgcn_mfma_f32_16x16x32_bf16(pka1, fb1, acc_k[t], 0, 0, 0);
            acc_v[t] = __builtin_amdgcn_mfma_f32_16x16x32_bf16(pva0, fb0, acc_v[t], 0, 0, 0);
            acc_v[t] = __builtin_amdgcn_mfma_f32_16x16x32_bf16(pva1, fb1, acc_v[t], 0, 0, 0);
        }
    }

    // ---- epilogue: normalize, multiply by q, reduce over rows ----
    #pragma unroll
    for (int off = 1; off < 16; off <<= 1) {
        #pragma unroll
        for (int r = 0; r < 4; ++r) {
            lp_k[r] += __shfl_xor(lp_k[r], off);
            lp_v[r] += __shfl_xor(lp_v[r], off);
        }
    }
    float c[4] = {0.f, 0.f, 0.f, 0.f};
    #pragma unroll
    for (int r = 0; r < 4; ++r) {
        float ilk = 1.0f / lp_k[r];
        float ilv = 1.0f / lp_v[r];
        int qr = w * 16 + 4 * ag + r;
        int qswz = (qr & 7) << 4;
        #pragma unroll
        for (int t = 0; t < 4; ++t) {
            float qv = __bfloat162float(*(const __hip_bfloat16*)(
                (const char*)Qs + qr * 128 + (((t * 16 + arow) * 2) ^ qswz)));
            c[t] += (acc_k[t][r] * ilk + acc_v[t][r] * ilv) * qv;
        }
    }
    #pragma unroll
    for (int t = 0; t < 4; ++t) {
        c[t] += __shfl_xor(c[t], 16);
        c[t] += __shfl_xor(c[t], 32);
    }
    if (lane < 16) {
        #pragma unroll
        for (int t = 0; t < 4; ++t) part_s[w][t * 16 + lane] = c[t];
    }
    __syncthreads();
    if (tid < 64) {
        float t = part_s[0][tid] + part_s[1][tid] + part_s[2][tid] + part_s[3][tid];
        part[(size_t)blockIdx.x * 64 + tid] = t;
    }
}

// ---------------- deterministic final reduction ----------------
__global__ void reduce_kernel(const float* __restrict__ part, float* __restrict__ out) {
    int bh = blockIdx.x;     // 0..31
    int d  = threadIdx.x;    // 0..63
    float t = 0.f;
    for (int i = 0; i < 32; ++i)
        t += part[(size_t)(bh * 32 + i) * 64 + d];
    out[bh * 64 + d] = t;
}

extern "C" void kernel_launch(void* const* d_in, const int* in_sizes, int n_in,
                              void* d_out, int out_size, void* d_ws, size_t ws_size,
                              hipStream_t stream) {
    const float* value = (const float*)d_in[0];
    const float* key   = (const float*)d_in[1];
    const float* query = (const float*)d_in[2];
    const float* Wv    = (const float*)d_in[3];
    const float* bv    = (const float*)d_in[4];
    const float* Wk    = (const float*)d_in[5];
    const float* bk    = (const float*)d_in[6];
    const float* Wq    = (const float*)d_in[7];
    const float* bq    = (const float*)d_in[8];
    float* out = (float*)d_out;

    char* w = (char*)d_ws;
    __hip_bfloat16* Qh = (__hip_bfloat16*)(w);                       // 8 MB
    __hip_bfloat16* Kh = (__hip_bfloat16*)(w + (size_t)8  * 1024 * 1024);
    __hip_bfloat16* Vh = (__hip_bfloat16*)(w + (size_t)16 * 1024 * 1024);
    __hip_bfloat16* Ft = (__hip_bfloat16*)(w + (size_t)24 * 1024 * 1024);
    float*          part = (float*)      (w + (size_t)32 * 1024 * 1024);  // 1024*64 f32

    dim3 pg(Dq / 64, (Bq * Sq) / 64);  // (8, 128)
    proj_kernel<<<pg, 256, 0, stream>>>(query, Wq, bq, Qh);
    proj_kernel<<<pg, 256, 0, stream>>>(key,   Wk, bk, Kh);
    proj_kernel<<<pg, 256, 0, stream>>>(value, Wv, bv, Vh);

    fuse_t_kernel<<<1024, 256, 0, stream>>>(Kh, Vh, Ft);
    attn_kernel<<<1024, 256, 0, stream>>>(Qh, Kh, Vh, Ft, part);
    reduce_kernel<<<32, 64, 0, stream>>>(part, out);
}

// Round 3
// 248.183 us; speedup vs baseline: 10.7298x; 1.9625x over previous
//
#include <hip/hip_runtime.h>
#include <hip/hip_bf16.h>

#define Bq 4
#define Sq 2048
#define Dq 512
#define Hq 8
#define HDq 64

typedef __attribute__((ext_vector_type(8))) short short8;
typedef __attribute__((ext_vector_type(4))) float f32x4;

#if __has_builtin(__builtin_amdgcn_exp2f)
#define EXP2(x) __builtin_amdgcn_exp2f(x)
#else
#define EXP2(x) exp2f(x)
#endif

#define SCALE2 (0.125f * 1.44269504088896340736f)

__device__ __forceinline__ short8 cvt8(float4 a, float4 b) {
    union { __hip_bfloat16 h[8]; short8 s; } u;
    u.h[0] = __float2bfloat16(a.x); u.h[1] = __float2bfloat16(a.y);
    u.h[2] = __float2bfloat16(a.z); u.h[3] = __float2bfloat16(a.w);
    u.h[4] = __float2bfloat16(b.x); u.h[5] = __float2bfloat16(b.y);
    u.h[6] = __float2bfloat16(b.z); u.h[7] = __float2bfloat16(b.w);
    return u.s;
}

// ---------------- batched MFMA projection: O = X @ W^T + bias, bf16 head layout ----------------
// z selects (X, W, bias, O). 128x128 tile, BK=64, 4 waves (2x2), fused f32->bf16 cast in staging.
__global__ __launch_bounds__(256, 3)
void proj_kernel(const float* __restrict__ Xv, const float* __restrict__ Xk, const float* __restrict__ Xq,
                 const float* __restrict__ Wv, const float* __restrict__ Wk, const float* __restrict__ Wq,
                 const float* __restrict__ bv, const float* __restrict__ bk, const float* __restrict__ bq,
                 __hip_bfloat16* __restrict__ Ov, __hip_bfloat16* __restrict__ Ok, __hip_bfloat16* __restrict__ Oq) {
    __shared__ alignas(16) short As[128 * 64];
    __shared__ alignas(16) short Bs[128 * 64];

    const int z = blockIdx.z;
    const float* X   = (z == 0) ? Xv : (z == 1) ? Xk : Xq;
    const float* W   = (z == 0) ? Wv : (z == 1) ? Wk : Wq;
    const float* bia = (z == 0) ? bv : (z == 1) ? bk : bq;
    __hip_bfloat16* O = (z == 0) ? Ov : (z == 1) ? Ok : Oq;

    const int tid  = threadIdx.x;
    const int lane = tid & 63;
    const int w    = tid >> 6;
    const int wr   = w >> 1;
    const int wc   = w & 1;
    const int m0   = blockIdx.y * 128;
    const int n0   = blockIdx.x * 128;
    const int arow = lane & 15;
    const int ag   = lane >> 4;

    f32x4 acc[4][4];
    #pragma unroll
    for (int t = 0; t < 4; ++t)
        #pragma unroll
        for (int u = 0; u < 4; ++u) acc[t][u] = (f32x4){0.f, 0.f, 0.f, 0.f};

    for (int kk = 0; kk < Dq / 64; ++kk) {
        __syncthreads();
        #pragma unroll
        for (int p = 0; p < 4; ++p) {
            int id  = p * 256 + tid;
            int row = id >> 3;
            int c   = id & 7;
            int dst = row * 128 + ((c * 16) ^ ((row & 7) << 4));
            const float* ax = X + (size_t)(m0 + row) * Dq + kk * 64 + c * 8;
            const float* bx = W + (size_t)(n0 + row) * Dq + kk * 64 + c * 8;
            float4 a0 = *(const float4*)ax;
            float4 a1 = *(const float4*)(ax + 4);
            float4 b0 = *(const float4*)bx;
            float4 b1 = *(const float4*)(bx + 4);
            *(short8*)((char*)As + dst) = cvt8(a0, a1);
            *(short8*)((char*)Bs + dst) = cvt8(b0, b1);
        }
        __syncthreads();
        #pragma unroll
        for (int h = 0; h < 2; ++h) {
            short8 af[4], bf[4];
            #pragma unroll
            for (int t = 0; t < 4; ++t) {
                int ra = wr * 64 + t * 16 + arow;
                int rb = wc * 64 + t * 16 + arow;
                af[t] = *(const short8*)((const char*)As + ra * 128 + ((h * 64 + ag * 16) ^ ((ra & 7) << 4)));
                bf[t] = *(const short8*)((const char*)Bs + rb * 128 + ((h * 64 + ag * 16) ^ ((rb & 7) << 4)));
            }
            #pragma unroll
            for (int t = 0; t < 4; ++t)
                #pragma unroll
                for (int u = 0; u < 4; ++u)
                    acc[t][u] = __builtin_amdgcn_mfma_f32_16x16x32_bf16(af[t], bf[u], acc[t][u], 0, 0, 0);
        }
    }

    float biasv[4];
    #pragma unroll
    for (int u = 0; u < 4; ++u) biasv[u] = bia[n0 + wc * 64 + u * 16 + arow];

    #pragma unroll
    for (int t = 0; t < 4; ++t) {
        #pragma unroll
        for (int u = 0; u < 4; ++u) {
            #pragma unroll
            for (int r = 0; r < 4; ++r) {
                int m = m0 + wr * 64 + t * 16 + 4 * ag + r;
                int n = n0 + wc * 64 + u * 16 + arow;
                int b = m >> 11, s = m & 2047;
                int hh = n >> 6, hd = n & 63;
                O[((((size_t)b * Hq + hh) * Sq + s) << 6) + hd] =
                    __float2bfloat16(acc[t][u][r] + biasv[u]);
            }
        }
    }
}

// ---------------- F^T = (K+V)^T per head: Ft[bh][d][s] ----------------
__global__ __launch_bounds__(256)
void fuse_t_kernel(const __hip_bfloat16* __restrict__ Kh, const __hip_bfloat16* __restrict__ Vh,
                   __hip_bfloat16* __restrict__ Ft) {
    __shared__ float T[64][65];
    const int bh = blockIdx.x >> 5;
    const int st = blockIdx.x & 31;
    const int tid = threadIdx.x;

    #pragma unroll
    for (int p = 0; p < 2; ++p) {
        int idx = p * 256 + tid;
        int r = idx >> 3;
        int c = (idx & 7) * 8;
        size_t g = ((size_t)bh * Sq + st * 64 + r) * 64 + c;
        float4 k4 = *(const float4*)((const char*)Kh + g * 2);
        float4 v4 = *(const float4*)((const char*)Vh + g * 2);
        const __hip_bfloat16* kp = (const __hip_bfloat16*)&k4;
        const __hip_bfloat16* vp = (const __hip_bfloat16*)&v4;
        #pragma unroll
        for (int j = 0; j < 8; ++j)
            T[r][c + j] = __bfloat162float(kp[j]) + __bfloat162float(vp[j]);
    }
    __syncthreads();
    #pragma unroll
    for (int p = 0; p < 2; ++p) {
        int idx = p * 256 + tid;
        int d  = idx >> 3;
        int s8 = (idx & 7) * 8;
        alignas(16) __hip_bfloat16 tmp[8];
        #pragma unroll
        for (int j = 0; j < 8; ++j) tmp[j] = __float2bfloat16(T[s8 + j][d]);
        *(float4*)((char*)Ft + (((size_t)bh * 64 + d) * Sq + st * 64 + s8) * 2) = *(const float4*)tmp;
    }
}

// ---------------- MFMA attention: 1 block = 1 (b,h) x 64 q-rows, 4 waves ----------------
__global__ __launch_bounds__(256)
void attn_kernel(const __hip_bfloat16* __restrict__ Qh, const __hip_bfloat16* __restrict__ Kh,
                 const __hip_bfloat16* __restrict__ Vh, const __hip_bfloat16* __restrict__ Ft,
                 float* __restrict__ part) {
    __shared__ alignas(16) short Qs[64 * 64];
    __shared__ alignas(16) short Ks[64 * 64];
    __shared__ alignas(16) short Vs[64 * 64];
    __shared__ alignas(16) short Fs[64 * 64];
    __shared__ alignas(16) short Pk[4 * 16 * 64];
    __shared__ alignas(16) short Pv[4 * 16 * 64];
    __shared__ float part_s[4][64];

    const int tid  = threadIdx.x;
    const int lane = tid & 63;
    const int w    = tid >> 6;
    const int bh   = blockIdx.x >> 5;
    const int s0   = (blockIdx.x & 31) * 64;

    const char* Qbh = (const char*)(Qh + (size_t)bh * Sq * 64);
    const char* Kbh = (const char*)(Kh + (size_t)bh * Sq * 64);
    const char* Vbh = (const char*)(Vh + (size_t)bh * Sq * 64);
    const char* Fbh = (const char*)(Ft + (size_t)bh * 64 * Sq);

    #pragma unroll
    for (int p = 0; p < 2; ++p) {
        int idx = p * 256 + tid;
        int r = idx >> 3;
        int c = idx & 7;
        int swz = (r & 7) << 4;
        float4 q4 = *(const float4*)(Qbh + ((size_t)(s0 + r) * 64 + c * 8) * 2);
        *(float4*)((char*)Qs + r * 128 + ((c * 16) ^ swz)) = q4;
    }
    __syncthreads();

    const int arow = lane & 15;
    const int ag   = lane >> 4;
    const int aswz = (arow & 7) << 4;

    const int qrow = w * 16 + arow;
    short8 qa0 = *(const short8*)((const char*)Qs + qrow * 128 + ((16 * ag) ^ aswz));
    short8 qa1 = *(const short8*)((const char*)Qs + qrow * 128 + ((64 + 16 * ag) ^ aswz));

    char* PkW = (char*)Pk + w * 2048;
    char* PvW = (char*)Pv + w * 2048;

    f32x4 acc_k[4], acc_v[4];
    #pragma unroll
    for (int t = 0; t < 4; ++t) {
        acc_k[t] = (f32x4){0.f, 0.f, 0.f, 0.f};
        acc_v[t] = (f32x4){0.f, 0.f, 0.f, 0.f};
    }
    float m_k[4], m_v[4], lp_k[4], lp_v[4];
    #pragma unroll
    for (int r = 0; r < 4; ++r) {
        m_k[r] = -INFINITY; m_v[r] = -INFINITY;
        lp_k[r] = 0.f; lp_v[r] = 0.f;
    }

    for (int ck = 0; ck < Sq / 64; ++ck) {
        const int kv0 = ck * 64;
        __syncthreads();
        #pragma unroll
        for (int p = 0; p < 2; ++p) {
            int idx = p * 256 + tid;
            int r = idx >> 3;
            int c = idx & 7;
            int swz = (r & 7) << 4;
            float4 k4 = *(const float4*)(Kbh + ((size_t)(kv0 + r) * 64 + c * 8) * 2);
            float4 v4 = *(const float4*)(Vbh + ((size_t)(kv0 + r) * 64 + c * 8) * 2);
            float4 f4 = *(const float4*)(Fbh + ((size_t)r * Sq + kv0 + c * 8) * 2);
            *(float4*)((char*)Ks + r * 128 + ((c * 16) ^ swz)) = k4;
            *(float4*)((char*)Vs + r * 128 + ((c * 16) ^ swz)) = v4;
            *(float4*)((char*)Fs + r * 128 + ((c * 16) ^ swz)) = f4;
        }
        __syncthreads();

        f32x4 sk[4], sv[4];
        #pragma unroll
        for (int t = 0; t < 4; ++t) {
            sk[t] = (f32x4){0.f, 0.f, 0.f, 0.f};
            sv[t] = (f32x4){0.f, 0.f, 0.f, 0.f};
        }
        #pragma unroll
        for (int t = 0; t < 4; ++t) {
            int brow = t * 16 + arow;
            int bswz = (brow & 7) << 4;
            short8 kb0 = *(const short8*)((const char*)Ks + brow * 128 + ((16 * ag) ^ bswz));
            short8 kb1 = *(const short8*)((const char*)Ks + brow * 128 + ((64 + 16 * ag) ^ bswz));
            short8 vb0 = *(const short8*)((const char*)Vs + brow * 128 + ((16 * ag) ^ bswz));
            short8 vb1 = *(const short8*)((const char*)Vs + brow * 128 + ((64 + 16 * ag) ^ bswz));
            sk[t] = __builtin_amdgcn_mfma_f32_16x16x32_bf16(qa0, kb0, sk[t], 0, 0, 0);
            sk[t] = __builtin_amdgcn_mfma_f32_16x16x32_bf16(qa1, kb1, sk[t], 0, 0, 0);
            sv[t] = __builtin_amdgcn_mfma_f32_16x16x32_bf16(qa0, vb0, sv[t], 0, 0, 0);
            sv[t] = __builtin_amdgcn_mfma_f32_16x16x32_bf16(qa1, vb1, sv[t], 0, 0, 0);
        }

        float cmk[4], cmv[4];
        #pragma unroll
        for (int r = 0; r < 4; ++r) {
            #pragma unroll
            for (int t = 0; t < 4; ++t) { sk[t][r] *= SCALE2; sv[t][r] *= SCALE2; }
            cmk[r] = fmaxf(fmaxf(sk[0][r], sk[1][r]), fmaxf(sk[2][r], sk[3][r]));
            cmv[r] = fmaxf(fmaxf(sv[0][r], sv[1][r]), fmaxf(sv[2][r], sv[3][r]));
        }
        #pragma unroll
        for (int off = 1; off < 16; off <<= 1) {
            #pragma unroll
            for (int r = 0; r < 4; ++r) {
                cmk[r] = fmaxf(cmk[r], __shfl_xor(cmk[r], off));
                cmv[r] = fmaxf(cmv[r], __shfl_xor(cmv[r], off));
            }
        }
        #pragma unroll
        for (int r = 0; r < 4; ++r) {
            if (cmk[r] > m_k[r] + 8.f) {
                float f = EXP2(m_k[r] - cmk[r]);
                m_k[r] = cmk[r]; lp_k[r] *= f;
                #pragma unroll
                for (int t = 0; t < 4; ++t) acc_k[t][r] *= f;
            }
            if (cmv[r] > m_v[r] + 8.f) {
                float f = EXP2(m_v[r] - cmv[r]);
                m_v[r] = cmv[r]; lp_v[r] *= f;
                #pragma unroll
                for (int t = 0; t < 4; ++t) acc_v[t][r] *= f;
            }
        }
        #pragma unroll
        for (int t = 0; t < 4; ++t) {
            #pragma unroll
            for (int r = 0; r < 4; ++r) {
                float pk = EXP2(sk[t][r] - m_k[r]);
                float pv = EXP2(sv[t][r] - m_v[r]);
                lp_k[r] += pk; lp_v[r] += pv;
                int row = 4 * ag + r;
                int col2 = (t * 16 + arow) * 2;
                int rswz = (row & 7) << 4;
                *(__hip_bfloat16*)(PkW + row * 128 + (col2 ^ rswz)) = __float2bfloat16(pk);
                *(__hip_bfloat16*)(PvW + row * 128 + (col2 ^ rswz)) = __float2bfloat16(pv);
            }
        }
        // NOTE: no barrier here — Pk/Pv are per-wave regions; same-wave RAW is
        // ordered by lgkmcnt. Staged Ks/Vs/Fs stay valid until next top barrier.

        short8 pka0 = *(const short8*)(PkW + arow * 128 + ((16 * ag) ^ aswz));
        short8 pka1 = *(const short8*)(PkW + arow * 128 + ((64 + 16 * ag) ^ aswz));
        short8 pva0 = *(const short8*)(PvW + arow * 128 + ((16 * ag) ^ aswz));
        short8 pva1 = *(const short8*)(PvW + arow * 128 + ((64 + 16 * ag) ^ aswz));
        #pragma unroll
        for (int t = 0; t < 4; ++t) {
            int brow = t * 16 + arow;
            int bswz = (brow & 7) << 4;
            short8 fb0 = *(const short8*)((const char*)Fs + brow * 128 + ((16 * ag) ^ bswz));
            short8 fb1 = *(const short8*)((const char*)Fs + brow * 128 + ((64 + 16 * ag) ^ bswz));
            acc_k[t] = __builtin_amdgcn_mfma_f32_16x16x32_bf16(pka0, fb0, acc_k[t], 0, 0, 0);
            acc_k[t] = __builtin_amdgcn_mfma_f32_16x16x32_bf16(pka1, fb1, acc_k[t], 0, 0, 0);
            acc_v[t] = __builtin_amdgcn_mfma_f32_16x16x32_bf16(pva0, fb0, acc_v[t], 0, 0, 0);
            acc_v[t] = __builtin_amdgcn_mfma_f32_16x16x32_bf16(pva1, fb1, acc_v[t], 0, 0, 0);
        }
    }

    #pragma unroll
    for (int off = 1; off < 16; off <<= 1) {
        #pragma unroll
        for (int r = 0; r < 4; ++r) {
            lp_k[r] += __shfl_xor(lp_k[r], off);
            lp_v[r] += __shfl_xor(lp_v[r], off);
        }
    }
    float c[4] = {0.f, 0.f, 0.f, 0.f};
    #pragma unroll
    for (int r = 0; r < 4; ++r) {
        float ilk = 1.0f / lp_k[r];
        float ilv = 1.0f / lp_v[r];
        int qr = w * 16 + 4 * ag + r;
        int qswz = (qr & 7) << 4;
        #pragma unroll
        for (int t = 0; t < 4; ++t) {
            float qv = __bfloat162float(*(const __hip_bfloat16*)(
                (const char*)Qs + qr * 128 + (((t * 16 + arow) * 2) ^ qswz)));
            c[t] += (acc_k[t][r] * ilk + acc_v[t][r] * ilv) * qv;
        }
    }
    #pragma unroll
    for (int t = 0; t < 4; ++t) {
        c[t] += __shfl_xor(c[t], 16);
        c[t] += __shfl_xor(c[t], 32);
    }
    if (lane < 16) {
        #pragma unroll
        for (int t = 0; t < 4; ++t) part_s[w][t * 16 + lane] = c[t];
    }
    __syncthreads();
    if (tid < 64) {
        float t = part_s[0][tid] + part_s[1][tid] + part_s[2][tid] + part_s[3][tid];
        part[(size_t)blockIdx.x * 64 + tid] = t;
    }
}

// ---------------- deterministic final reduction ----------------
__global__ void reduce_kernel(const float* __restrict__ part, float* __restrict__ out) {
    int bh = blockIdx.x;
    int d  = threadIdx.x;
    float t = 0.f;
    for (int i = 0; i < 32; ++i)
        t += part[(size_t)(bh * 32 + i) * 64 + d];
    out[bh * 64 + d] = t;
}

extern "C" void kernel_launch(void* const* d_in, const int* in_sizes, int n_in,
                              void* d_out, int out_size, void* d_ws, size_t ws_size,
                              hipStream_t stream) {
    const float* value = (const float*)d_in[0];
    const float* key   = (const float*)d_in[1];
    const float* query = (const float*)d_in[2];
    const float* Wv    = (const float*)d_in[3];
    const float* bv    = (const float*)d_in[4];
    const float* Wk    = (const float*)d_in[5];
    const float* bk    = (const float*)d_in[6];
    const float* Wq    = (const float*)d_in[7];
    const float* bq    = (const float*)d_in[8];
    float* out = (float*)d_out;

    char* w = (char*)d_ws;
    __hip_bfloat16* Qh = (__hip_bfloat16*)(w);
    __hip_bfloat16* Kh = (__hip_bfloat16*)(w + (size_t)8  * 1024 * 1024);
    __hip_bfloat16* Vh = (__hip_bfloat16*)(w + (size_t)16 * 1024 * 1024);
    __hip_bfloat16* Ft = (__hip_bfloat16*)(w + (size_t)24 * 1024 * 1024);
    float*          part = (float*)      (w + (size_t)32 * 1024 * 1024);

    dim3 pg(Dq / 128, (Bq * Sq) / 128, 3);  // (4, 64, 3)
    proj_kernel<<<pg, 256, 0, stream>>>(value, key, query, Wv, Wk, Wq, bv, bk, bq, Vh, Kh, Qh);

    fuse_t_kernel<<<1024, 256, 0, stream>>>(Kh, Vh, Ft);
    attn_kernel<<<1024, 256, 0, stream>>>(Qh, Kh, Vh, Ft, part);
    reduce_kernel<<<32, 64, 0, stream>>>(part, out);
}